// Round 4
// baseline (75.474 us; speedup 1.0000x reference)
//
#include <hip/hip_runtime.h>

// Problem constants (fixed by the reference)
#define C8     8      // feat channels
#define KOBJ   32     // objects per image
#define BIMG   8      // batch
#define WW     128
#define HWPIX  16384  // H*W
#define CWN    169    // conv params per object
#define TQ     4      // quarter-tiles per (b,k): each block does 4096 px
#define SLOTS_PER_B (KOBJ * TQ)     // 128 partial slots per image
#define NB     (BIMG * SLOTS_PER_B) // 1024 blocks

// Weight layout within the 169-vector (row-major reshapes):
//  c1w: [8][10] at 0..79   (in = 8 seg channels, x_rel, y_rel)
//  c1b: 80..87
//  c2w: [8][8]  at 88..151
//  c2b: 152..159
//  c3w: [8]     at 160..167
//  c3b: 168

__global__ __launch_bounds__(256, 3) void mask_head_kernel(
    const float* __restrict__ seg_feat,    // [B,8,H,W]
    const float* __restrict__ conv_weight, // [B,169,H,W]
    const int* __restrict__ mask,          // [B,K]
    const long long* __restrict__ ind,     // [B,K]
    const float* __restrict__ target,      // [B,K,H,W]
    float* __restrict__ partial)           // [B][128][3]
{
    // Decode so consecutive blocks are DIFFERENT pairs (k fastest):
    // round-robin XCD dispatch then mixes active/masked pairs evenly.
    const int id   = blockIdx.x;
    const int k    = id & (KOBJ - 1);
    const int rest = id >> 5;
    const int b    = rest & (BIMG - 1);
    const int t4   = rest >> 3;          // quarter-tile 0..3
    const int t    = threadIdx.x;

    float* my = partial + (b * SLOTS_PER_B + k * TQ + t4) * 3;

    // Masked-out objects contribute exactly zero to all sums.
    if (mask[b * KOBJ + k] == 0) {
        if (t < 3) my[t] = 0.f;
        return;
    }

    // Padded weight layout for broadcast vector LDS reads.
    __shared__ __align__(16) float l1w[C8][12];  // [o][c], c<10 valid
    __shared__ __align__(16) float l1b[C8];
    __shared__ __align__(16) float l2w[C8][C8];
    __shared__ __align__(16) float l2b[C8];
    __shared__ __align__(16) float l3w[C8];
    __shared__ float l3b_s;
    __shared__ float red[4][3];

    const int idx = (int)ind[b * KOBJ + k];
    if (t < CWN) {
        const float v = conv_weight[(b * CWN + t) * HWPIX + idx];
        if (t < 80)       { l1w[t / 10][t % 10] = v; }
        else if (t < 88)  { l1b[t - 80] = v; }
        else if (t < 152) { const int u = t - 88; l2w[u >> 3][u & 7] = v; }
        else if (t < 160) { l2b[t - 152] = v; }
        else if (t < 168) { l3w[t - 160] = v; }
        else              { l3b_s = v; }
    }
    __syncthreads();

    const float cx = (float)(idx & (WW - 1));
    const float cy = (float)(idx >> 7);

    const float* seg = seg_feat + b * C8 * HWPIX;
    const float* tgt = target + (b * KOBJ + k) * HWPIX;

    const int colbase = (t & 31) * 4;    // float4-aligned column
    const int rsub    = t >> 5;          // 0..7 row within batch stripe

    float sx[4];
#pragma unroll
    for (int i = 0; i < 4; ++i) sx[i] = ((float)(colbase + i) - cx) * (1.0f / 128.0f);

    float s_pt = 0.f, s_pp = 0.f, s_tt = 0.f;

#pragma unroll
    for (int b4 = 0; b4 < 4; ++b4) {
        const int row = t4 * 32 + b4 * 8 + rsub;
        const int px  = row * WW + colbase;

        // prefetch target (latency hidden under MLP)
        const float4 tv4 = *reinterpret_cast<const float4*>(&tgt[px]);
        const float sy = ((float)row - cy) * (1.0f / 128.0f);

        // seg features: one float4 per channel
        float f[C8][4];
#pragma unroll
        for (int c = 0; c < C8; ++c) {
            const float4 a = *reinterpret_cast<const float4*>(&seg[c * HWPIX + px]);
            f[c][0] = a.x; f[c][1] = a.y; f[c][2] = a.z; f[c][3] = a.w;
        }

        // layer 1: 10 -> 8, relu (wy*sy folded into per-o base)
        float h1[C8][4];
#pragma unroll
        for (int o = 0; o < C8; ++o) {
            const float4 wa = *reinterpret_cast<const float4*>(&l1w[o][0]);
            const float4 wb = *reinterpret_cast<const float4*>(&l1w[o][4]);
            const float4 wc = *reinterpret_cast<const float4*>(&l1w[o][8]); // .x=wx,.y=wy
            const float base = fmaf(wc.y, sy, l1b[o]);
#pragma unroll
            for (int i = 0; i < 4; ++i) {
                float a = fmaf(wc.x, sx[i], base);
                a = fmaf(wa.x, f[0][i], a);
                a = fmaf(wa.y, f[1][i], a);
                a = fmaf(wa.z, f[2][i], a);
                a = fmaf(wa.w, f[3][i], a);
                a = fmaf(wb.x, f[4][i], a);
                a = fmaf(wb.y, f[5][i], a);
                a = fmaf(wb.z, f[6][i], a);
                a = fmaf(wb.w, f[7][i], a);
                h1[o][i] = fmaxf(a, 0.f);
            }
        }

        // layer 2: 8 -> 8, relu
        float h2[C8][4];
#pragma unroll
        for (int o = 0; o < C8; ++o) {
            const float4 wa = *reinterpret_cast<const float4*>(&l2w[o][0]);
            const float4 wb = *reinterpret_cast<const float4*>(&l2w[o][4]);
            const float bias = l2b[o];
#pragma unroll
            for (int i = 0; i < 4; ++i) {
                float a = bias;
                a = fmaf(wa.x, h1[0][i], a);
                a = fmaf(wa.y, h1[1][i], a);
                a = fmaf(wa.z, h1[2][i], a);
                a = fmaf(wa.w, h1[3][i], a);
                a = fmaf(wb.x, h1[4][i], a);
                a = fmaf(wb.y, h1[5][i], a);
                a = fmaf(wb.z, h1[6][i], a);
                a = fmaf(wb.w, h1[7][i], a);
                h2[o][i] = fmaxf(a, 0.f);
            }
        }

        // layer 3: 8 -> 1, sigmoid; fuse dice partial sums
        const float4 wa = *reinterpret_cast<const float4*>(&l3w[0]);
        const float4 wb = *reinterpret_cast<const float4*>(&l3w[4]);
        const float b3 = l3b_s;
        float tvv[4];
        tvv[0] = tv4.x; tvv[1] = tv4.y; tvv[2] = tv4.z; tvv[3] = tv4.w;
#pragma unroll
        for (int i = 0; i < 4; ++i) {
            float z = b3;
            z = fmaf(wa.x, h2[0][i], z);
            z = fmaf(wa.y, h2[1][i], z);
            z = fmaf(wa.z, h2[2][i], z);
            z = fmaf(wa.w, h2[3][i], z);
            z = fmaf(wb.x, h2[4][i], z);
            z = fmaf(wb.y, h2[5][i], z);
            z = fmaf(wb.z, h2[6][i], z);
            z = fmaf(wb.w, h2[7][i], z);
            const float e    = __expf(-z);
            const float pred = __builtin_amdgcn_rcpf(1.0f + e);
            s_pt = fmaf(pred, tvv[i], s_pt);
            s_pp = fmaf(pred, pred, s_pp);
            s_tt = fmaf(tvv[i], tvv[i], s_tt);
        }
    }

    // wave reduction (64-wide), then block reduction via LDS
#pragma unroll
    for (int off = 32; off > 0; off >>= 1) {
        s_pt += __shfl_down(s_pt, off);
        s_pp += __shfl_down(s_pp, off);
        s_tt += __shfl_down(s_tt, off);
    }
    const int wid = t >> 6;
    if ((t & 63) == 0) { red[wid][0] = s_pt; red[wid][1] = s_pp; red[wid][2] = s_tt; }
    __syncthreads();
    if (t == 0) {
        float a = 0.f, b2 = 0.f, c2 = 0.f;
#pragma unroll
        for (int i = 0; i < 4; ++i) { a += red[i][0]; b2 += red[i][1]; c2 += red[i][2]; }
        my[0] = a; my[1] = b2; my[2] = c2;
    }
}

__global__ __launch_bounds__(256) void finalize_kernel(
    const float* __restrict__ partial, float* __restrict__ out)
{
    const int t    = threadIdx.x;
    const int w    = t >> 6;   // wave 0..3
    const int lane = t & 63;
    __shared__ float per[BIMG];

    for (int img = w; img < BIMG; img += 4) {
        const float* base = partial + img * SLOTS_PER_B * 3;
        float pt = 0.f, pp = 0.f, tt = 0.f;
        for (int s = lane; s < SLOTS_PER_B; s += 64) {
            pt += base[s * 3 + 0];
            pp += base[s * 3 + 1];
            tt += base[s * 3 + 2];
        }
#pragma unroll
        for (int off = 32; off > 0; off >>= 1) {
            pt += __shfl_down(pt, off);
            pp += __shfl_down(pp, off);
            tt += __shfl_down(tt, off);
        }
        if (lane == 0) per[img] = 1.0f - (2.0f * pt + 1.0f) / (pp + tt + 1.0f);
    }
    __syncthreads();
    if (t == 0) {
        float s = 0.f;
#pragma unroll
        for (int i = 0; i < BIMG; ++i) s += per[i];
        out[0] = s * (1.0f / (float)BIMG);
    }
}

extern "C" void kernel_launch(void* const* d_in, const int* in_sizes, int n_in,
                              void* d_out, int out_size, void* d_ws, size_t ws_size,
                              hipStream_t stream) {
    const float*     seg  = (const float*)d_in[0];
    const float*     cw   = (const float*)d_in[1];
    const int*       mask = (const int*)d_in[2];
    const long long* ind  = (const long long*)d_in[3];
    const float*     tgt  = (const float*)d_in[4];
    float* out     = (float*)d_out;
    float* partial = (float*)d_ws;   // NB*3 floats = 12 KiB

    mask_head_kernel<<<dim3(NB), 256, 0, stream>>>(seg, cw, mask, ind, tgt, partial);
    finalize_kernel<<<1, 256, 0, stream>>>(partial, out);
}

// Round 5
// 60.853 us; speedup vs baseline: 1.2403x; 1.2403x over previous
//
#include <hip/hip_runtime.h>

// Problem constants (fixed by the reference)
#define C8     8      // feat channels
#define KOBJ   32     // objects per image
#define BIMG   8      // batch
#define WW     128
#define HWPIX  16384  // H*W
#define CWN    169    // conv params per object
#define PIX    8      // contiguous pixels per thread
#define GRIDX  8      // pixel tiles per (b,k): 8 * 256 * PIX = 16384
#define SLOTS_PER_B (KOBJ * GRIDX)      // 256 partial slots per image
#define NBLK   (BIMG * SLOTS_PER_B)     // 2048 blocks

// Weight layout within the 169-vector (row-major reshapes):
//  c1w: [8][10] at 0..79   (in = 8 seg channels, x_rel, y_rel)
//  c1b: 80..87
//  c2w: [8][8]  at 88..151
//  c2b: 152..159
//  c3w: [8]     at 160..167
//  c3b: 168

__global__ __launch_bounds__(256) void mask_head_kernel(
    const float* __restrict__ seg_feat,    // [B,8,H,W]
    const float* __restrict__ conv_weight, // [B,169,H,W]
    const int* __restrict__ mask,          // [B,K]
    const long long* __restrict__ ind,     // [B,K]
    const float* __restrict__ target,      // [B,K,H,W]
    float* __restrict__ partial,           // [NBLK][3]
    unsigned int* __restrict__ counter,    // zeroed by memset node each launch
    float* __restrict__ out)
{
    const int tile = blockIdx.x;
    const int k    = blockIdx.y;
    const int b    = blockIdx.z;
    const int t    = threadIdx.x;
    const int blockFlat = (b * KOBJ + k) * GRIDX + tile;
    float* my = partial + blockFlat * 3;

    __shared__ __align__(16) float l1w[C8][12];  // [o][c], c<10 valid
    __shared__ __align__(16) float l1b[C8];
    __shared__ __align__(16) float l2w[C8][C8];
    __shared__ __align__(16) float l2b[C8];
    __shared__ __align__(16) float l3w[C8];
    __shared__ float l3b_s;
    __shared__ float red[4][3];
    __shared__ bool amLast;

    const bool active = (mask[b * KOBJ + k] != 0);

    if (active) {
        const int idx = (int)ind[b * KOBJ + k];
        if (t < CWN) {
            const float v = conv_weight[(b * CWN + t) * HWPIX + idx];
            if (t < 80)       { l1w[t / 10][t % 10] = v; }
            else if (t < 88)  { l1b[t - 80] = v; }
            else if (t < 152) { const int u = t - 88; l2w[u >> 3][u & 7] = v; }
            else if (t < 160) { l2b[t - 152] = v; }
            else if (t < 168) { l3w[t - 160] = v; }
            else              { l3b_s = v; }
        }
        __syncthreads();

        const float cx = (float)(idx & (WW - 1));
        const float cy = (float)(idx >> 7);

        const float* seg = seg_feat + b * C8 * HWPIX;
        const float* tgt = target + (b * KOBJ + k) * HWPIX;

        const int p0 = (tile * 256 + t) * PIX;   // 8 contiguous pixels, same row

        // Prefetch target early (latency hidden under the MLP).
        const float4 t4a = *reinterpret_cast<const float4*>(&tgt[p0]);
        const float4 t4b = *reinterpret_cast<const float4*>(&tgt[p0 + 4]);

        // relative coordinates: same row for all 8 pixels
        const float sy  = ((float)(p0 >> 7) - cy) * (1.0f / 128.0f);
        const float sx0 = ((float)(p0 & (WW - 1)) - cx) * (1.0f / 128.0f);
        float sx[PIX];
#pragma unroll
        for (int i = 0; i < PIX; ++i) sx[i] = sx0 + (float)i * (1.0f / 128.0f);

        // seg features: 2x float4 per channel
        float f[C8][PIX];
#pragma unroll
        for (int c = 0; c < C8; ++c) {
            const float4 a = *reinterpret_cast<const float4*>(&seg[c * HWPIX + p0]);
            const float4 d = *reinterpret_cast<const float4*>(&seg[c * HWPIX + p0 + 4]);
            f[c][0] = a.x; f[c][1] = a.y; f[c][2] = a.z; f[c][3] = a.w;
            f[c][4] = d.x; f[c][5] = d.y; f[c][6] = d.z; f[c][7] = d.w;
        }

        // layer 1: 10 -> 8, relu   (wy*sy folded into per-o base)
        float h1[C8][PIX];
#pragma unroll
        for (int o = 0; o < C8; ++o) {
            const float4 wa = *reinterpret_cast<const float4*>(&l1w[o][0]);
            const float4 wb = *reinterpret_cast<const float4*>(&l1w[o][4]);
            const float4 wc = *reinterpret_cast<const float4*>(&l1w[o][8]); // .x=wx,.y=wy
            const float base = fmaf(wc.y, sy, l1b[o]);
#pragma unroll
            for (int i = 0; i < PIX; ++i) {
                float a = fmaf(wc.x, sx[i], base);
                a = fmaf(wa.x, f[0][i], a);
                a = fmaf(wa.y, f[1][i], a);
                a = fmaf(wa.z, f[2][i], a);
                a = fmaf(wa.w, f[3][i], a);
                a = fmaf(wb.x, f[4][i], a);
                a = fmaf(wb.y, f[5][i], a);
                a = fmaf(wb.z, f[6][i], a);
                a = fmaf(wb.w, f[7][i], a);
                h1[o][i] = fmaxf(a, 0.f);
            }
        }

        // layers 2+3 fused: h2 is transient per output channel
        float z[PIX];
        {
            const float b3 = l3b_s;
#pragma unroll
            for (int i = 0; i < PIX; ++i) z[i] = b3;
        }
#pragma unroll
        for (int o = 0; o < C8; ++o) {
            const float4 wa = *reinterpret_cast<const float4*>(&l2w[o][0]);
            const float4 wb = *reinterpret_cast<const float4*>(&l2w[o][4]);
            const float bias = l2b[o];
            const float w3 = l3w[o];
#pragma unroll
            for (int i = 0; i < PIX; ++i) {
                float a = bias;
                a = fmaf(wa.x, h1[0][i], a);
                a = fmaf(wa.y, h1[1][i], a);
                a = fmaf(wa.z, h1[2][i], a);
                a = fmaf(wa.w, h1[3][i], a);
                a = fmaf(wb.x, h1[4][i], a);
                a = fmaf(wb.y, h1[5][i], a);
                a = fmaf(wb.z, h1[6][i], a);
                a = fmaf(wb.w, h1[7][i], a);
                z[i] = fmaf(w3, fmaxf(a, 0.f), z[i]);
            }
        }

        float tv[PIX];
        tv[0] = t4a.x; tv[1] = t4a.y; tv[2] = t4a.z; tv[3] = t4a.w;
        tv[4] = t4b.x; tv[5] = t4b.y; tv[6] = t4b.z; tv[7] = t4b.w;

        float s_pt = 0.f, s_pp = 0.f, s_tt = 0.f;
#pragma unroll
        for (int i = 0; i < PIX; ++i) {
            const float e    = __expf(-z[i]);
            const float pred = __builtin_amdgcn_rcpf(1.0f + e);
            s_pt = fmaf(pred, tv[i], s_pt);
            s_pp = fmaf(pred, pred, s_pp);
            s_tt = fmaf(tv[i], tv[i], s_tt);
        }

        // wave reduction (64-wide), then block reduction via LDS
#pragma unroll
        for (int off = 32; off > 0; off >>= 1) {
            s_pt += __shfl_down(s_pt, off);
            s_pp += __shfl_down(s_pp, off);
            s_tt += __shfl_down(s_tt, off);
        }
        const int wid = t >> 6;
        if ((t & 63) == 0) { red[wid][0] = s_pt; red[wid][1] = s_pp; red[wid][2] = s_tt; }
        __syncthreads();
        if (t == 0) {
            float a = 0.f, b2 = 0.f, c2 = 0.f;
#pragma unroll
            for (int i = 0; i < 4; ++i) { a += red[i][0]; b2 += red[i][1]; c2 += red[i][2]; }
            my[0] = a; my[1] = b2; my[2] = c2;
        }
    } else {
        if (t == 0) { my[0] = 0.f; my[1] = 0.f; my[2] = 0.f; }
    }

    // ---- last-block finalize (device-scope, deterministic) ----
    if (t == 0) {
        __threadfence();                       // release partial stores
        const unsigned prev = atomicAdd(counter, 1u);
        amLast = (prev == (unsigned)(NBLK - 1));
    }
    __syncthreads();
    if (!amLast) return;
    __threadfence();                           // acquire all partials

    const int w    = t >> 6;   // wave 0..3
    const int lane = t & 63;
    __shared__ float per[BIMG];
    for (int img = w; img < BIMG; img += 4) {
        const float* base = partial + img * SLOTS_PER_B * 3;
        float pt = 0.f, pp = 0.f, tt = 0.f;
        for (int s = lane; s < SLOTS_PER_B; s += 64) {
            pt += base[s * 3 + 0];
            pp += base[s * 3 + 1];
            tt += base[s * 3 + 2];
        }
#pragma unroll
        for (int off = 32; off > 0; off >>= 1) {
            pt += __shfl_down(pt, off);
            pp += __shfl_down(pp, off);
            tt += __shfl_down(tt, off);
        }
        if (lane == 0) per[img] = 1.0f - (2.0f * pt + 1.0f) / (pp + tt + 1.0f);
    }
    __syncthreads();
    if (t == 0) {
        float s = 0.f;
#pragma unroll
        for (int i = 0; i < BIMG; ++i) s += per[i];
        out[0] = s * (1.0f / (float)BIMG);
    }
}

extern "C" void kernel_launch(void* const* d_in, const int* in_sizes, int n_in,
                              void* d_out, int out_size, void* d_ws, size_t ws_size,
                              hipStream_t stream) {
    const float*     seg  = (const float*)d_in[0];
    const float*     cw   = (const float*)d_in[1];
    const int*       mask = (const int*)d_in[2];
    const long long* ind  = (const long long*)d_in[3];
    const float*     tgt  = (const float*)d_in[4];
    float* out = (float*)d_out;

    unsigned int* counter = (unsigned int*)d_ws;                 // 4 B at offset 0
    float* partial = (float*)((char*)d_ws + 16);                 // NBLK*3 floats = 24 KiB

    hipMemsetAsync(counter, 0, sizeof(unsigned int), stream);    // graph memset node
    mask_head_kernel<<<dim3(GRIDX, KOBJ, BIMG), 256, 0, stream>>>(
        seg, cw, mask, ind, tgt, partial, counter, out);
}

// Round 6
// 58.657 us; speedup vs baseline: 1.2867x; 1.0374x over previous
//
#include <hip/hip_runtime.h>

// Problem constants (fixed by the reference)
#define C8     8      // feat channels
#define KOBJ   32     // objects per image
#define BIMG   8      // batch
#define WW     128
#define HWPIX  16384  // H*W
#define CWN    169    // conv params per object
#define PIX    8      // contiguous pixels per thread
#define GRIDX  8      // pixel tiles per (b,k): 8 * 256 * PIX = 16384
#define NBLK   (BIMG * KOBJ * GRIDX)    // 2048 blocks

// Weight layout within the 169-vector (row-major reshapes):
//  c1w: [8][10] at 0..79   (in = 8 seg channels, x_rel, y_rel)
//  c1b: 80..87
//  c2w: [8][8]  at 88..151
//  c2b: 152..159
//  c3w: [8]     at 160..167
//  c3b: 168

__global__ __launch_bounds__(256) void mask_head_kernel(
    const float* __restrict__ seg_feat,    // [B,8,H,W]
    const float* __restrict__ conv_weight, // [B,169,H,W]
    const int* __restrict__ mask,          // [B,K]
    const long long* __restrict__ ind,     // [B,K]
    const float* __restrict__ target,      // [B,K,H,W]
    unsigned int* __restrict__ counter,    // zeroed by memset node each launch
    float* __restrict__ acc,               // [BIMG][3], zeroed each launch
    float* __restrict__ out)
{
    const int tile = blockIdx.x;
    const int k    = blockIdx.y;
    const int b    = blockIdx.z;
    const int t    = threadIdx.x;

    __shared__ __align__(16) float l1w[C8][12];  // [o][c], c<10 valid
    __shared__ __align__(16) float l1b[C8];
    __shared__ __align__(16) float l2w[C8][C8];
    __shared__ __align__(16) float l2b[C8];
    __shared__ __align__(16) float l3w[C8];
    __shared__ float l3b_s;
    __shared__ float red[4][3];
    __shared__ float accs[BIMG * 3];
    __shared__ bool amLast;

    const bool active = (mask[b * KOBJ + k] != 0);

    if (active) {
        const int idx = (int)ind[b * KOBJ + k];
        if (t < CWN) {
            const float v = conv_weight[(b * CWN + t) * HWPIX + idx];
            if (t < 80)       { l1w[t / 10][t % 10] = v; }
            else if (t < 88)  { l1b[t - 80] = v; }
            else if (t < 152) { const int u = t - 88; l2w[u >> 3][u & 7] = v; }
            else if (t < 160) { l2b[t - 152] = v; }
            else if (t < 168) { l3w[t - 160] = v; }
            else              { l3b_s = v; }
        }
        __syncthreads();

        const float cx = (float)(idx & (WW - 1));
        const float cy = (float)(idx >> 7);

        const float* seg = seg_feat + b * C8 * HWPIX;
        const float* tgt = target + (b * KOBJ + k) * HWPIX;

        const int p0 = (tile * 256 + t) * PIX;   // 8 contiguous pixels, same row

        // Prefetch target early (latency hidden under the MLP).
        const float4 t4a = *reinterpret_cast<const float4*>(&tgt[p0]);
        const float4 t4b = *reinterpret_cast<const float4*>(&tgt[p0 + 4]);

        // relative coordinates: same row for all 8 pixels
        const float sy  = ((float)(p0 >> 7) - cy) * (1.0f / 128.0f);
        const float sx0 = ((float)(p0 & (WW - 1)) - cx) * (1.0f / 128.0f);
        float sx[PIX];
#pragma unroll
        for (int i = 0; i < PIX; ++i) sx[i] = sx0 + (float)i * (1.0f / 128.0f);

        // seg features: 2x float4 per channel
        float f[C8][PIX];
#pragma unroll
        for (int c = 0; c < C8; ++c) {
            const float4 a = *reinterpret_cast<const float4*>(&seg[c * HWPIX + p0]);
            const float4 d = *reinterpret_cast<const float4*>(&seg[c * HWPIX + p0 + 4]);
            f[c][0] = a.x; f[c][1] = a.y; f[c][2] = a.z; f[c][3] = a.w;
            f[c][4] = d.x; f[c][5] = d.y; f[c][6] = d.z; f[c][7] = d.w;
        }

        // layer 1: 10 -> 8, relu   (wy*sy folded into per-o base)
        float h1[C8][PIX];
#pragma unroll
        for (int o = 0; o < C8; ++o) {
            const float4 wa = *reinterpret_cast<const float4*>(&l1w[o][0]);
            const float4 wb = *reinterpret_cast<const float4*>(&l1w[o][4]);
            const float4 wc = *reinterpret_cast<const float4*>(&l1w[o][8]); // .x=wx,.y=wy
            const float base = fmaf(wc.y, sy, l1b[o]);
#pragma unroll
            for (int i = 0; i < PIX; ++i) {
                float a = fmaf(wc.x, sx[i], base);
                a = fmaf(wa.x, f[0][i], a);
                a = fmaf(wa.y, f[1][i], a);
                a = fmaf(wa.z, f[2][i], a);
                a = fmaf(wa.w, f[3][i], a);
                a = fmaf(wb.x, f[4][i], a);
                a = fmaf(wb.y, f[5][i], a);
                a = fmaf(wb.z, f[6][i], a);
                a = fmaf(wb.w, f[7][i], a);
                h1[o][i] = fmaxf(a, 0.f);
            }
        }

        // layers 2+3 fused: h2 is transient per output channel
        float z[PIX];
        {
            const float b3 = l3b_s;
#pragma unroll
            for (int i = 0; i < PIX; ++i) z[i] = b3;
        }
#pragma unroll
        for (int o = 0; o < C8; ++o) {
            const float4 wa = *reinterpret_cast<const float4*>(&l2w[o][0]);
            const float4 wb = *reinterpret_cast<const float4*>(&l2w[o][4]);
            const float bias = l2b[o];
            const float w3 = l3w[o];
#pragma unroll
            for (int i = 0; i < PIX; ++i) {
                float a = bias;
                a = fmaf(wa.x, h1[0][i], a);
                a = fmaf(wa.y, h1[1][i], a);
                a = fmaf(wa.z, h1[2][i], a);
                a = fmaf(wa.w, h1[3][i], a);
                a = fmaf(wb.x, h1[4][i], a);
                a = fmaf(wb.y, h1[5][i], a);
                a = fmaf(wb.z, h1[6][i], a);
                a = fmaf(wb.w, h1[7][i], a);
                z[i] = fmaf(w3, fmaxf(a, 0.f), z[i]);
            }
        }

        float tv[PIX];
        tv[0] = t4a.x; tv[1] = t4a.y; tv[2] = t4a.z; tv[3] = t4a.w;
        tv[4] = t4b.x; tv[5] = t4b.y; tv[6] = t4b.z; tv[7] = t4b.w;

        float s_pt = 0.f, s_pp = 0.f, s_tt = 0.f;
#pragma unroll
        for (int i = 0; i < PIX; ++i) {
            const float e    = __expf(-z[i]);
            const float pred = __builtin_amdgcn_rcpf(1.0f + e);
            s_pt = fmaf(pred, tv[i], s_pt);
            s_pp = fmaf(pred, pred, s_pp);
            s_tt = fmaf(tv[i], tv[i], s_tt);
        }

        // wave reduction (64-wide), then block reduction via LDS
#pragma unroll
        for (int off = 32; off > 0; off >>= 1) {
            s_pt += __shfl_down(s_pt, off);
            s_pp += __shfl_down(s_pp, off);
            s_tt += __shfl_down(s_tt, off);
        }
        const int wid = t >> 6;
        if ((t & 63) == 0) { red[wid][0] = s_pt; red[wid][1] = s_pp; red[wid][2] = s_tt; }
        __syncthreads();

        if (t == 0) {
            float a = 0.f, b2 = 0.f, c2 = 0.f;
#pragma unroll
            for (int i = 0; i < 4; ++i) { a += red[i][0]; b2 += red[i][1]; c2 += red[i][2]; }
            // Device-scope atomic accumulation: performed at the coherent
            // point, no cache flush needed (unlike __threadfence).
            const float r0 = atomicAdd(&acc[b * 3 + 0], a);
            const float r1 = atomicAdd(&acc[b * 3 + 1], b2);
            const float r2 = atomicAdd(&acc[b * 3 + 2], c2);
            // Data-dependency fence: counter increment depends on the
            // returned old values, so the wave waits (vmcnt) for the float
            // atomics to complete at the coherent point before signaling.
            unsigned inc = 1u;
            asm volatile("" : "+v"(inc) : "v"(r0), "v"(r1), "v"(r2));
            const unsigned prev = atomicAdd(counter, inc);
            amLast = (prev == (unsigned)(NBLK - 1));
        }
    } else {
        if (t == 0) {
            const unsigned prev = atomicAdd(counter, 1u);
            amLast = (prev == (unsigned)(NBLK - 1));
        }
    }

    __syncthreads();
    if (!amLast) return;

    // ---- last block: finalize from coherent-point reads ----
    if (t < BIMG * 3) {
        accs[t] = __hip_atomic_load(&acc[t], __ATOMIC_RELAXED, __HIP_MEMORY_SCOPE_AGENT);
    }
    __syncthreads();
    if (t == 0) {
        float s = 0.f;
#pragma unroll
        for (int i = 0; i < BIMG; ++i) {
            const float pt = accs[i * 3 + 0];
            const float pp = accs[i * 3 + 1];
            const float tt = accs[i * 3 + 2];
            s += 1.0f - (2.0f * pt + 1.0f) / (pp + tt + 1.0f);
        }
        out[0] = s * (1.0f / (float)BIMG);
    }
}

extern "C" void kernel_launch(void* const* d_in, const int* in_sizes, int n_in,
                              void* d_out, int out_size, void* d_ws, size_t ws_size,
                              hipStream_t stream) {
    const float*     seg  = (const float*)d_in[0];
    const float*     cw   = (const float*)d_in[1];
    const int*       mask = (const int*)d_in[2];
    const long long* ind  = (const long long*)d_in[3];
    const float*     tgt  = (const float*)d_in[4];
    float* out = (float*)d_out;

    unsigned int* counter = (unsigned int*)d_ws;          // 4 B at offset 0
    float* acc = (float*)((char*)d_ws + 16);              // 24 floats at offset 16

    // Zero counter + accumulators every launch (single graph memset node).
    hipMemsetAsync(d_ws, 0, 112, stream);
    mask_head_kernel<<<dim3(GRIDX, KOBJ, BIMG), 256, 0, stream>>>(
        seg, cw, mask, ind, tgt, counter, acc, out);
}

// Round 7
// 26.221 us; speedup vs baseline: 2.8783x; 2.2370x over previous
//
#include <hip/hip_runtime.h>

// Problem constants (fixed by the reference)
#define C8     8      // feat channels
#define KOBJ   32     // objects per image
#define BIMG   8      // batch
#define WW     128
#define HWPIX  16384  // H*W
#define CWN    169    // conv params per object
#define PIX    8      // contiguous pixels per thread
#define GRIDX  8      // pixel tiles per (b,k): 8 * 256 * PIX = 16384

// acc layout: acc[b*32 + j], j in {0,1,2} -> each image on its own 128B line
#define ACC_STRIDE 32

// Weight layout within the 169-vector (row-major reshapes):
//  c1w: [8][10] at 0..79   (in = 8 seg channels, x_rel, y_rel)
//  c1b: 80..87
//  c2w: [8][8]  at 88..151
//  c2b: 152..159
//  c3w: [8]     at 160..167
//  c3b: 168

__global__ __launch_bounds__(256) void mask_head_kernel(
    const float* __restrict__ seg_feat,    // [B,8,H,W]
    const float* __restrict__ conv_weight, // [B,169,H,W]
    const int* __restrict__ mask,          // [B,K]
    const long long* __restrict__ ind,     // [B,K]
    const float* __restrict__ target,      // [B,K,H,W]
    float* __restrict__ acc)               // [BIMG][ACC_STRIDE], zeroed each launch
{
    const int tile = blockIdx.x;
    const int k    = blockIdx.y;
    const int b    = blockIdx.z;
    const int t    = threadIdx.x;

    // Masked-out objects contribute exactly zero: no work, no stores.
    if (mask[b * KOBJ + k] == 0) return;

    __shared__ __align__(16) float l1w[C8][12];  // [o][c], c<10 valid
    __shared__ __align__(16) float l1b[C8];
    __shared__ __align__(16) float l2w[C8][C8];
    __shared__ __align__(16) float l2b[C8];
    __shared__ __align__(16) float l3w[C8];
    __shared__ float l3b_s;
    __shared__ float red[4][3];

    const int idx = (int)ind[b * KOBJ + k];
    if (t < CWN) {
        const float v = conv_weight[(b * CWN + t) * HWPIX + idx];
        if (t < 80)       { l1w[t / 10][t % 10] = v; }
        else if (t < 88)  { l1b[t - 80] = v; }
        else if (t < 152) { const int u = t - 88; l2w[u >> 3][u & 7] = v; }
        else if (t < 160) { l2b[t - 152] = v; }
        else if (t < 168) { l3w[t - 160] = v; }
        else              { l3b_s = v; }
    }
    __syncthreads();

    const float cx = (float)(idx & (WW - 1));
    const float cy = (float)(idx >> 7);

    const float* seg = seg_feat + b * C8 * HWPIX;
    const float* tgt = target + (b * KOBJ + k) * HWPIX;

    const int p0 = (tile * 256 + t) * PIX;   // 8 contiguous pixels, same row

    // Prefetch target early (latency hidden under the MLP).
    const float4 t4a = *reinterpret_cast<const float4*>(&tgt[p0]);
    const float4 t4b = *reinterpret_cast<const float4*>(&tgt[p0 + 4]);

    // relative coordinates: same row for all 8 pixels
    const float sy  = ((float)(p0 >> 7) - cy) * (1.0f / 128.0f);
    const float sx0 = ((float)(p0 & (WW - 1)) - cx) * (1.0f / 128.0f);
    float sx[PIX];
#pragma unroll
    for (int i = 0; i < PIX; ++i) sx[i] = sx0 + (float)i * (1.0f / 128.0f);

    // seg features: 2x float4 per channel
    float f[C8][PIX];
#pragma unroll
    for (int c = 0; c < C8; ++c) {
        const float4 a = *reinterpret_cast<const float4*>(&seg[c * HWPIX + p0]);
        const float4 d = *reinterpret_cast<const float4*>(&seg[c * HWPIX + p0 + 4]);
        f[c][0] = a.x; f[c][1] = a.y; f[c][2] = a.z; f[c][3] = a.w;
        f[c][4] = d.x; f[c][5] = d.y; f[c][6] = d.z; f[c][7] = d.w;
    }

    // layer 1: 10 -> 8, relu   (wy*sy folded into per-o base)
    float h1[C8][PIX];
#pragma unroll
    for (int o = 0; o < C8; ++o) {
        const float4 wa = *reinterpret_cast<const float4*>(&l1w[o][0]);
        const float4 wb = *reinterpret_cast<const float4*>(&l1w[o][4]);
        const float4 wc = *reinterpret_cast<const float4*>(&l1w[o][8]); // .x=wx,.y=wy
        const float base = fmaf(wc.y, sy, l1b[o]);
#pragma unroll
        for (int i = 0; i < PIX; ++i) {
            float a = fmaf(wc.x, sx[i], base);
            a = fmaf(wa.x, f[0][i], a);
            a = fmaf(wa.y, f[1][i], a);
            a = fmaf(wa.z, f[2][i], a);
            a = fmaf(wa.w, f[3][i], a);
            a = fmaf(wb.x, f[4][i], a);
            a = fmaf(wb.y, f[5][i], a);
            a = fmaf(wb.z, f[6][i], a);
            a = fmaf(wb.w, f[7][i], a);
            h1[o][i] = fmaxf(a, 0.f);
        }
    }

    // layers 2+3 fused: h2 is transient per output channel
    float z[PIX];
    {
        const float b3 = l3b_s;
#pragma unroll
        for (int i = 0; i < PIX; ++i) z[i] = b3;
    }
#pragma unroll
    for (int o = 0; o < C8; ++o) {
        const float4 wa = *reinterpret_cast<const float4*>(&l2w[o][0]);
        const float4 wb = *reinterpret_cast<const float4*>(&l2w[o][4]);
        const float bias = l2b[o];
        const float w3 = l3w[o];
#pragma unroll
        for (int i = 0; i < PIX; ++i) {
            float a = bias;
            a = fmaf(wa.x, h1[0][i], a);
            a = fmaf(wa.y, h1[1][i], a);
            a = fmaf(wa.z, h1[2][i], a);
            a = fmaf(wa.w, h1[3][i], a);
            a = fmaf(wb.x, h1[4][i], a);
            a = fmaf(wb.y, h1[5][i], a);
            a = fmaf(wb.z, h1[6][i], a);
            a = fmaf(wb.w, h1[7][i], a);
            z[i] = fmaf(w3, fmaxf(a, 0.f), z[i]);
        }
    }

    float tv[PIX];
    tv[0] = t4a.x; tv[1] = t4a.y; tv[2] = t4a.z; tv[3] = t4a.w;
    tv[4] = t4b.x; tv[5] = t4b.y; tv[6] = t4b.z; tv[7] = t4b.w;

    float s_pt = 0.f, s_pp = 0.f, s_tt = 0.f;
#pragma unroll
    for (int i = 0; i < PIX; ++i) {
        const float e    = __expf(-z[i]);
        const float pred = __builtin_amdgcn_rcpf(1.0f + e);
        s_pt = fmaf(pred, tv[i], s_pt);
        s_pp = fmaf(pred, pred, s_pp);
        s_tt = fmaf(tv[i], tv[i], s_tt);
    }

    // wave reduction (64-wide), then block reduction via LDS
#pragma unroll
    for (int off = 32; off > 0; off >>= 1) {
        s_pt += __shfl_down(s_pt, off);
        s_pp += __shfl_down(s_pp, off);
        s_tt += __shfl_down(s_tt, off);
    }
    const int wid = t >> 6;
    if ((t & 63) == 0) { red[wid][0] = s_pt; red[wid][1] = s_pp; red[wid][2] = s_tt; }
    __syncthreads();
    if (t == 0) {
        float a = 0.f, b2 = 0.f, c2 = 0.f;
#pragma unroll
        for (int i = 0; i < 4; ++i) { a += red[i][0]; b2 += red[i][1]; c2 += red[i][2]; }
        // 3 device-scope float atomics per active block, 8 images on
        // separate 128B lines -> ~128-way contention per address, pipelined.
        atomicAdd(&acc[b * ACC_STRIDE + 0], a);
        atomicAdd(&acc[b * ACC_STRIDE + 1], b2);
        atomicAdd(&acc[b * ACC_STRIDE + 2], c2);
    }
}

__global__ __launch_bounds__(64) void finalize_kernel(
    const float* __restrict__ acc, float* __restrict__ out)
{
    const int lane = threadIdx.x;
    float li = 0.f;
    if (lane < BIMG) {
        const float pt = acc[lane * ACC_STRIDE + 0];
        const float pp = acc[lane * ACC_STRIDE + 1];
        const float tt = acc[lane * ACC_STRIDE + 2];
        li = 1.0f - (2.0f * pt + 1.0f) / (pp + tt + 1.0f);
    }
#pragma unroll
    for (int off = 4; off > 0; off >>= 1) li += __shfl_down(li, off);
    if (lane == 0) out[0] = li * (1.0f / (float)BIMG);
}

extern "C" void kernel_launch(void* const* d_in, const int* in_sizes, int n_in,
                              void* d_out, int out_size, void* d_ws, size_t ws_size,
                              hipStream_t stream) {
    const float*     seg  = (const float*)d_in[0];
    const float*     cw   = (const float*)d_in[1];
    const int*       mask = (const int*)d_in[2];
    const long long* ind  = (const long long*)d_in[3];
    const float*     tgt  = (const float*)d_in[4];
    float* out = (float*)d_out;
    float* acc = (float*)d_ws;   // [BIMG][ACC_STRIDE] floats = 1 KiB

    hipMemsetAsync(acc, 0, BIMG * ACC_STRIDE * sizeof(float), stream);
    mask_head_kernel<<<dim3(GRIDX, KOBJ, BIMG), 256, 0, stream>>>(
        seg, cw, mask, ind, tgt, acc);
    finalize_kernel<<<1, 64, 0, stream>>>(acc, out);
}

// Round 8
// 21.015 us; speedup vs baseline: 3.5914x; 1.2477x over previous
//
#include <hip/hip_runtime.h>

typedef float f32x2 __attribute__((ext_vector_type(2)));

// Problem constants (fixed by the reference)
#define C8     8      // feat channels
#define KOBJ   32     // objects per image
#define BIMG   8      // batch
#define WW     128
#define HWPIX  16384  // H*W
#define CWN    169    // conv params per object
#define PIX    8      // contiguous pixels per thread (2 batches of 4)
#define GRIDX  8      // tiles per (b,k)
#define NPAIR  (BIMG * KOBJ)            // 256
#define SLOTS_PER_B (KOBJ * GRIDX)      // 256 slots per image
#define NBLK   (NPAIR * GRIDX)          // 2048 blocks / slots

// D = S0*S1 + D  (packed 2x fp32 FMA, IEEE-identical to fmaf)
__device__ __forceinline__ void pkfma(f32x2& d, f32x2 a, f32x2 b) {
    asm("v_pk_fma_f32 %0, %1, %2, %0" : "+v"(d) : "v"(a), "v"(b));
}

__global__ __launch_bounds__(256) void mask_head_kernel(
    const float* __restrict__ seg_feat,    // [B,8,H,W]
    const float* __restrict__ conv_weight, // [B,169,H,W]
    const int* __restrict__ mask,          // [B,K]
    const long long* __restrict__ ind,     // [B,K]
    const float* __restrict__ target,      // [B,K,H,W]
    float* __restrict__ partial)           // [NBLK][3]
{
    const int j    = blockIdx.x;
    const int r    = j >> 3;       // pair rank
    const int tile = j & 7;
    const int t    = threadIdx.x;

    // Duplicated weights ({w,w}) so one ds_read_b64 yields a pk broadcast.
    __shared__ f32x2 wd1[C8][10];   // [o][c]: c 0..7 seg, 8 = wx, 9 = wy
    __shared__ f32x2 l1b2[C8];
    __shared__ f32x2 wd2[C8][C8];
    __shared__ f32x2 l2b2[C8];
    __shared__ f32x2 w3d[C8];
    __shared__ float b3s;
    __shared__ float red[4][3];
    __shared__ int   sh_pair, sh_active;

    // ---- wave-0 compaction scan: rank r -> r-th active (or masked) pair ----
    if (t < 64) {
        const int lane = t;
        const int4 mv = *reinterpret_cast<const int4*>(&mask[lane * 4]);
        const int a0 = (mv.x != 0), a1 = (mv.y != 0), a2 = (mv.z != 0), a3 = (mv.w != 0);
        const int c0 = a0 + a1 + a2 + a3;
        int incl = c0;
#pragma unroll
        for (int off = 1; off < 64; off <<= 1) {
            const int n = __shfl_up(incl, off);
            if (lane >= off) incl += n;
        }
        const int excl  = incl - c0;
        const int total = __shfl(incl, 63);
        const int use_act = (r < total) ? 1 : 0;
        const int rr   = use_act ? r : (r - total);
        const int base = use_act ? excl : (4 * lane - excl);
        const int cnt  = use_act ? c0 : (4 - c0);
        const bool has = (rr >= base) && (rr < base + cnt);
        const int w0 = use_act ? a0 : 1 - a0;
        const int w1 = use_act ? a1 : 1 - a1;
        const int w2 = use_act ? a2 : 1 - a2;
        const int d  = rr - base;
        const int s0 = w0, s1 = w0 + w1, s2 = w0 + w1 + w2;
        const int off4 = (d < s0) ? 0 : (d < s1) ? 1 : (d < s2) ? 2 : 3;
        const int pcand = lane * 4 + off4;
        const unsigned long long bal = __ballot(has);
        const int src = (int)__ffsll((long long)bal) - 1;
        const int pv = __shfl(pcand, src);
        if (lane == 0) { sh_pair = pv; sh_active = use_act; }
    }
    __syncthreads();

    const int pair = sh_pair;
    const int slot = pair * GRIDX + tile;       // = (b*32+k)*8 + tile
    if (!sh_active) {
        if (t < 3) partial[slot * 3 + t] = 0.f; // masked pair: exact zero
        return;
    }

    const int b = pair >> 5;
    const int idx = (int)ind[pair];

    // ---- gather 169 params, write duplicated ----
    if (t < CWN) {
        const float v = conv_weight[(b * CWN + t) * HWPIX + idx];
        const f32x2 v2 = {v, v};
        if (t < 80)       { wd1[t / 10][t % 10] = v2; }
        else if (t < 88)  { l1b2[t - 80] = v2; }
        else if (t < 152) { const int u = t - 88; wd2[u >> 3][u & 7] = v2; }
        else if (t < 160) { l2b2[t - 152] = v2; }
        else if (t < 168) { w3d[t - 160] = v2; }
        else              { b3s = v; }
    }
    __syncthreads();

    const float cx = (float)(idx & (WW - 1));
    const float cy = (float)(idx >> 7);

    const float* seg = seg_feat + b * C8 * HWPIX;
    const float* tgt = target + pair * HWPIX;

    const int p0   = tile * 2048 + t * PIX;   // 8 contiguous px, same row
    const int row  = p0 >> 7;
    const int col0 = p0 & (WW - 1);
    const float sy = ((float)row - cy) * (1.0f / 128.0f);
    const f32x2 sy2 = {sy, sy};

    // prefetch both target float4s early
    const float4 tA = *reinterpret_cast<const float4*>(&tgt[p0]);
    const float4 tB = *reinterpret_cast<const float4*>(&tgt[p0 + 4]);

    float s_pt = 0.f, s_pp = 0.f, s_tt = 0.f;

#pragma unroll
    for (int h = 0; h < 2; ++h) {             // two 4-pixel sub-batches
        const int q = p0 + h * 4;
        const float colq = (float)(col0 + h * 4);
        const f32x2 sxa = {(colq - cx) * (1.0f / 128.0f),
                           (colq + 1.0f - cx) * (1.0f / 128.0f)};
        const f32x2 sxb = {(colq + 2.0f - cx) * (1.0f / 128.0f),
                           (colq + 3.0f - cx) * (1.0f / 128.0f)};

        // seg features: one float4 per channel -> two f32x2
        f32x2 f2[C8][2];
#pragma unroll
        for (int c = 0; c < C8; ++c) {
            const float4 a = *reinterpret_cast<const float4*>(&seg[c * HWPIX + q]);
            f2[c][0] = {a.x, a.y};
            f2[c][1] = {a.z, a.w};
        }

        // layer 1: 10 -> 8, relu
        f32x2 h1[C8][2];
#pragma unroll
        for (int o = 0; o < C8; ++o) {
            f32x2 base2 = l1b2[o];
            pkfma(base2, wd1[o][9], sy2);     // += wy*sy
            f32x2 acc0 = base2, acc1 = base2;
            pkfma(acc0, wd1[o][8], sxa);      // += wx*sx
            pkfma(acc1, wd1[o][8], sxb);
#pragma unroll
            for (int c = 0; c < C8; ++c) {
                const f32x2 w = wd1[o][c];
                pkfma(acc0, w, f2[c][0]);
                pkfma(acc1, w, f2[c][1]);
            }
            h1[o][0] = {fmaxf(acc0.x, 0.f), fmaxf(acc0.y, 0.f)};
            h1[o][1] = {fmaxf(acc1.x, 0.f), fmaxf(acc1.y, 0.f)};
        }

        // layers 2+3 fused
        f32x2 z0 = {b3s, b3s}, z1 = z0;
#pragma unroll
        for (int o = 0; o < C8; ++o) {
            f32x2 acc0 = l2b2[o], acc1 = l2b2[o];
#pragma unroll
            for (int c = 0; c < C8; ++c) {
                const f32x2 w = wd2[o][c];
                pkfma(acc0, w, h1[c][0]);
                pkfma(acc1, w, h1[c][1]);
            }
            const f32x2 r0 = {fmaxf(acc0.x, 0.f), fmaxf(acc0.y, 0.f)};
            const f32x2 r1 = {fmaxf(acc1.x, 0.f), fmaxf(acc1.y, 0.f)};
            const f32x2 w3 = w3d[o];
            pkfma(z0, w3, r0);
            pkfma(z1, w3, r1);
        }

        // sigmoid + dice partials (4 px)
        const float zz[4] = {z0.x, z0.y, z1.x, z1.y};
        const float4 tq = (h == 0) ? tA : tB;
        const float tv[4] = {tq.x, tq.y, tq.z, tq.w};
#pragma unroll
        for (int i = 0; i < 4; ++i) {
            const float e    = __expf(-zz[i]);
            const float pred = __builtin_amdgcn_rcpf(1.0f + e);
            s_pt = fmaf(pred, tv[i], s_pt);
            s_pp = fmaf(pred, pred, s_pp);
            s_tt = fmaf(tv[i], tv[i], s_tt);
        }
    }

    // wave reduction, then block reduction via LDS
#pragma unroll
    for (int off = 32; off > 0; off >>= 1) {
        s_pt += __shfl_down(s_pt, off);
        s_pp += __shfl_down(s_pp, off);
        s_tt += __shfl_down(s_tt, off);
    }
    const int wid = t >> 6;
    if ((t & 63) == 0) { red[wid][0] = s_pt; red[wid][1] = s_pp; red[wid][2] = s_tt; }
    __syncthreads();
    if (t == 0) {
        float a = 0.f, b2 = 0.f, c2 = 0.f;
#pragma unroll
        for (int i = 0; i < 4; ++i) { a += red[i][0]; b2 += red[i][1]; c2 += red[i][2]; }
        partial[slot * 3 + 0] = a;
        partial[slot * 3 + 1] = b2;
        partial[slot * 3 + 2] = c2;
    }
}

__global__ __launch_bounds__(512) void finalize_kernel(
    const float* __restrict__ partial, float* __restrict__ out)
{
    const int t    = threadIdx.x;
    const int b    = t >> 6;   // one wave per image
    const int lane = t & 63;

    float pt = 0.f, pp = 0.f, tt = 0.f;
    for (int e = lane; e < SLOTS_PER_B; e += 64) {
        const float* q = partial + (b * SLOTS_PER_B + e) * 3;
        pt += q[0]; pp += q[1]; tt += q[2];
    }
#pragma unroll
    for (int off = 32; off > 0; off >>= 1) {
        pt += __shfl_down(pt, off);
        pp += __shfl_down(pp, off);
        tt += __shfl_down(tt, off);
    }
    __shared__ float per[BIMG];
    if (lane == 0) {
        per[b] = 1.0f - (2.0f * pt + 1.0f) / (pp + tt + 1.0f);
    }
    __syncthreads();
    if (t == 0) {
        float s = 0.f;
#pragma unroll
        for (int i = 0; i < BIMG; ++i) s += per[i];
        out[0] = s * (1.0f / (float)BIMG);
    }
}

extern "C" void kernel_launch(void* const* d_in, const int* in_sizes, int n_in,
                              void* d_out, int out_size, void* d_ws, size_t ws_size,
                              hipStream_t stream) {
    const float*     seg  = (const float*)d_in[0];
    const float*     cw   = (const float*)d_in[1];
    const int*       mask = (const int*)d_in[2];
    const long long* ind  = (const long long*)d_in[3];
    const float*     tgt  = (const float*)d_in[4];
    float* out     = (float*)d_out;
    float* partial = (float*)d_ws;   // NBLK*3 floats = 24 KiB

    mask_head_kernel<<<dim3(NBLK), 256, 0, stream>>>(seg, cw, mask, ind, tgt, partial);
    finalize_kernel<<<1, 512, 0, stream>>>(partial, out);
}